// Round 6
// baseline (334.797 us; speedup 1.0000x reference)
//
#include <hip/hip_runtime.h>
#include <stdint.h>

#define NB 8
#define F_IN 6300
#define NT 500
#define HID 32
#define NOUT 20
#define NW 99   // u64 mask words per (b,t) row: ceil(6300/64)

// float32 constants, rounded exactly as np.float32 would round the doubles
#define D_SR   0.7788007830714049f     // exp(-1/4)
#define S_SR   0.6795704571147613f     // e/4
#define D_REF  0.36787944117144233f    // exp(-1)
#define C_REF  -5.43656365691809f      // -2*e

// ---------------- K0: transpose w1 [32][6300] -> w1td [6300][32] (f64) ----------------
// LDS-tiled: coalesced reads along f, coalesced writes along the flat output.
__global__ __launch_bounds__(256) void k0_transpose(const float* __restrict__ w1,
                                                    double* __restrict__ w1td) {
  __shared__ float tl[64][33];
  const int f0 = blockIdx.x * 64;
  const int tid = threadIdx.x;
  const int r = tid & 63, g = tid >> 6;      // r = f offset in tile, g = o sub-group
#pragma unroll
  for (int oo = 0; oo < 32; oo += 4) {
    int o = oo + g;
    int f = f0 + r;
    tl[r][o] = (f < F_IN) ? w1[o * F_IN + f] : 0.f;
  }
  __syncthreads();
#pragma unroll
  for (int k = 0; k < 8; k++) {
    int idx = k * 256 + tid;                 // 0..2047 within tile
    int rr = idx >> 5, cc = idx & 31;
    int f = f0 + rr;
    if (f < F_IN) w1td[(size_t)f * 32 + cc] = (double)tl[rr][cc];
  }
}

// ---------------- K1: layer 1 (psp -> spike), exact f32 ----------------
// One wave per (b, 64-f word); 1-wave blocks => no barriers. 5 chunks of 100 t.
// float4 loads ALONG t (coalesced), transposed through LDS tile[100][65];
// chunk c+1's global loads fly while chunk c computes.
#define CH_T 100

__global__ __launch_bounds__(64) void k1_layer1(const float* __restrict__ x,
                                                uint64_t* __restrict__ masks) {
  __shared__ float tile[CH_T][65];          // 26 KB -> 6 blocks/CU
  const int wi = blockIdx.x;                // 0..98
  const int b  = blockIdx.y;
  const int lane = threadIdx.x;
  const int f = wi * 64 + lane;
  const float vm = (f < F_IN) ? 1.0f : 0.0f;
  const float* xblk = x + (size_t)b * F_IN * NT;
  uint64_t* mrow = masks + ((size_t)b * NW + wi) * NT;   // contiguous in t

  // per-k load/deposit geometry: idx = k*64+lane in [0,1600) -> fid = idx/25, j = idx%25
  int goff[25], fidv[25], jv[25];
#pragma unroll
  for (int k = 0; k < 25; k++) {
    int idx = k * 64 + lane;
    int fid = idx / 25;
    int j = idx - fid * 25;
    int rf = wi * 64 + fid;
    if (rf >= F_IN) rf = F_IN - 1;          // clamp: in-bounds reads, zeroed by vm
    goff[k] = rf * NT + 4 * j;
    fidv[k] = fid;
    jv[k] = j;
  }

  float z1 = 0.f, y1 = 0.f, zr = 0.f, yr = 0.f;
  float4 ld[25];
#pragma unroll
  for (int k = 0; k < 25; k++) ld[k] = *(const float4*)(xblk + goff[k]);

  for (int c = 0; c < 5; c++) {
#pragma unroll
    for (int k = 0; k < 25; k++) {
      int r = 4 * jv[k], fd = fidv[k];
      tile[r + 0][fd] = ld[k].x;
      tile[r + 1][fd] = ld[k].y;
      tile[r + 2][fd] = ld[k].z;
      tile[r + 3][fd] = ld[k].w;
    }
    if (c + 1 < 5) {
      const float* gb = xblk + (c + 1) * CH_T;
#pragma unroll
      for (int k = 0; k < 25; k++) ld[k] = *(const float4*)(gb + goff[k]);
    }
    uint64_t keep0 = 0, keep1 = 0;
#pragma unroll
    for (int tc = 0; tc < CH_T; tc++) {
      float xi = tile[tc][lane] * vm;
      y1 = __fmul_rn(D_SR, __fadd_rn(y1, z1));        // y = d*(y+z)
      z1 = __fadd_rn(__fmul_rn(D_SR, z1), xi);        // z = d*z + x
      float p = __fmul_rn(S_SR, y1);
      yr = __fmul_rn(D_REF, __fadd_rn(yr, zr));
      float u = __fadd_rn(p, __fmul_rn(C_REF, yr));
      bool s = (u >= 1.0f);
      zr = __fadd_rn(__fmul_rn(D_REF, zr), s ? 1.0f : 0.0f);
      uint64_t m = __ballot(s);
      if (tc < 64) { if (lane == tc)      keep0 = m; }
      else         { if (lane == tc - 64) keep1 = m; }
    }
    uint64_t* mp = mrow + c * CH_T;
    mp[lane] = keep0;
    if (lane < CH_T - 64) mp[64 + lane] = keep1;
  }
}

// ---------------- K2: sparse fc1: R[b,o,t] = sum_{f active} w1td[f][o] (f64) ----------------
// One wave per (b,t); halves process even/odd u64 words as 2x32-bit sub-words.
// Per spike: ffbl + clear(2) + lshl_add + load(SGPR-base) + v_add_f64.
__global__ __launch_bounds__(256) void k2_fc1(const double* __restrict__ w1td,
                                              const uint64_t* __restrict__ masks,
                                              double* __restrict__ R) {
  const int lane = threadIdx.x & 63;
  const int wave = threadIdx.x >> 6;
  const int half = lane >> 5;
  const int o = lane & 31;
  const int b = blockIdx.x;
  const int t = blockIdx.y * 4 + wave;        // blockIdx.y 0..124
  const uint64_t* mbase = masks + (size_t)b * NW * NT + t;  // word wi at mbase[wi*NT]
  const char* wbase = (const char*)w1td + o * 8;
  double acc = 0.0;
  uint64_t mcur = mbase[(size_t)half * NT];
  for (int wi = half; wi < NW; wi += 2) {
    uint64_t mnext = (wi + 2 < NW) ? mbase[(size_t)(wi + 2) * NT] : 0;
    uint32_t lo = (uint32_t)mcur;
    uint32_t hi = (uint32_t)(mcur >> 32);
    uint32_t off0 = (uint32_t)wi * (64 * 256);   // byte offset of w1td[wi*64][0]
    while (lo) {
      int i = __builtin_ctz(lo);
      lo &= lo - 1;
      acc += *(const double*)(wbase + off0 + ((uint32_t)i << 8));
    }
    uint32_t off1 = off0 + 32 * 256;
    while (hi) {
      int i = __builtin_ctz(hi);
      hi &= hi - 1;
      acc += *(const double*)(wbase + off1 + ((uint32_t)i << 8));
    }
    mcur = mnext;
  }
  // combine the two halves (lane ^ 32)
  int hi2 = __shfl_xor(__double2hiint(acc), 32);
  int lo2 = __shfl_xor(__double2loint(acc), 32);
  acc += __hiloint2double(hi2, lo2);
  if (half == 0) R[((size_t)b * HID + o) * NT + t] = acc;
}

// ---------------- shared f64 psp+spike step (layers 2/3) ----------------
__device__ __forceinline__ bool snn_step(double ri, double& z2, double& y2,
                                         double& zr, double& yr) {
  const double dsr = (double)D_SR, ssr = (double)S_SR;
  const double dre = (double)D_REF, cr = (double)C_REF;
  y2 = dsr * (y2 + z2);
  z2 = dsr * z2 + ri;
  double p = ssr * y2;
  yr = dre * (yr + zr);
  double u = p + cr * yr;
  bool s = (u >= 1.0);
  zr = dre * zr + (s ? 1.0 : 0.0);
  return s;
}

// ---------------- K3: layer-2 psp filter + spike -> s2 bytes [b][t][h] ----------------
__global__ __launch_bounds__(64) void k3_spike2(const double* __restrict__ R,
                                                uint8_t* __restrict__ s2) {
  int id = blockIdx.x * 64 + threadIdx.x;    // 0..255
  int b = id >> 5, h = id & 31;
  const double2* r2 = (const double2*)(R + (size_t)id * NT);
  uint8_t* sp = s2 + (size_t)b * NT * HID + h;
  double z2 = 0, y2 = 0, zr = 0, yr = 0;
  double2 g0a = r2[0], g0b = r2[1];
  double2 g1a = r2[2], g1b = r2[3];
  double2 g2a = r2[4], g2b = r2[5];
  double2 g3a = r2[6], g3b = r2[7];
  for (int g = 0; g < 125; g++) {
    sp[0]       = snn_step(g0a.x, z2, y2, zr, yr) ? 1 : 0;
    sp[HID]     = snn_step(g0a.y, z2, y2, zr, yr) ? 1 : 0;
    sp[2 * HID] = snn_step(g0b.x, z2, y2, zr, yr) ? 1 : 0;
    sp[3 * HID] = snn_step(g0b.y, z2, y2, zr, yr) ? 1 : 0;
    sp += 4 * HID;
    g0a = g1a; g0b = g1b; g1a = g2a; g1b = g2b; g2a = g3a; g2b = g3b;
    if (g + 4 < 125) { g3a = r2[(g + 4) * 2]; g3b = r2[(g + 4) * 2 + 1]; }
  }
}

// ---------------- K4: R3[b,o,t] = sum_h w2[o,h] * s2[b,t,h] (f64) ----------------
__global__ __launch_bounds__(256) void k4_fc2(const float* __restrict__ w2,
                                              const uint8_t* __restrict__ s2,
                                              double* __restrict__ R3) {
  int id = blockIdx.x * 256 + threadIdx.x;
  if (id >= NB * NOUT * NT) return;
  int t = id % NT;
  int bo = id / NT;
  int o = bo % NOUT;
  int b = bo / NOUT;
  const uint8_t* row = s2 + (size_t)(b * NT + t) * HID;
  const float* wr = w2 + o * HID;
  double acc = 0.0;
#pragma unroll
  for (int h = 0; h < HID; h += 4) {
    uint32_t m = *(const uint32_t*)(row + h);
    float4 w = *(const float4*)(wr + h);
    if (m & 0x000000FFu) acc += (double)w.x;
    if (m & 0x0000FF00u) acc += (double)w.y;
    if (m & 0x00FF0000u) acc += (double)w.z;
    if (m & 0xFF000000u) acc += (double)w.w;
  }
  R3[(size_t)bo * NT + t] = acc;
}

// ---------------- K5: layer-3 psp filter + spike -> output f32 ----------------
__global__ __launch_bounds__(64) void k5_out(const double* __restrict__ R3,
                                             float* __restrict__ out) {
  int id = blockIdx.x * 64 + threadIdx.x;
  if (id >= NB * NOUT) return;
  const double2* r2 = (const double2*)(R3 + (size_t)id * NT);
  float* orow = out + (size_t)id * NT;
  double z2 = 0, y2 = 0, zr = 0, yr = 0;
  double2 g0a = r2[0], g0b = r2[1];
  double2 g1a = r2[2], g1b = r2[3];
  double2 g2a = r2[4], g2b = r2[5];
  double2 g3a = r2[6], g3b = r2[7];
  for (int g = 0; g < 125; g++) {
    orow[0] = snn_step(g0a.x, z2, y2, zr, yr) ? 1.0f : 0.0f;
    orow[1] = snn_step(g0a.y, z2, y2, zr, yr) ? 1.0f : 0.0f;
    orow[2] = snn_step(g0b.x, z2, y2, zr, yr) ? 1.0f : 0.0f;
    orow[3] = snn_step(g0b.y, z2, y2, zr, yr) ? 1.0f : 0.0f;
    orow += 4;
    g0a = g1a; g0b = g1b; g1a = g2a; g1b = g2b; g2a = g3a; g2b = g3b;
    if (g + 4 < 125) { g3a = r2[(g + 4) * 2]; g3b = r2[(g + 4) * 2 + 1]; }
  }
}

extern "C" void kernel_launch(void* const* d_in, const int* in_sizes, int n_in,
                              void* d_out, int out_size, void* d_ws, size_t ws_size,
                              hipStream_t stream) {
  const float* x  = (const float*)d_in[0];   // [8,6300,500]
  const float* w1 = (const float*)d_in[1];   // [32,6300]
  const float* w2 = (const float*)d_in[2];   // [20,32]
  float* out = (float*)d_out;                // [8,20,500]

  uint8_t* ws = (uint8_t*)d_ws;
  const size_t W1TD_BYTES = (size_t)F_IN * HID * 8;        // 1,612,800
  const size_t MASK_BYTES = (size_t)NB * NW * NT * 8;      // 3,168,000
  const size_t R_BYTES    = (size_t)NB * HID * NT * 8;     // 1,024,000
  const size_t S2_BYTES   = (size_t)NB * NT * HID;         //   128,000
  double*   w1td  = (double*)ws;
  uint64_t* masks = (uint64_t*)(ws + W1TD_BYTES);
  double*   R     = (double*)(ws + W1TD_BYTES + MASK_BYTES);
  uint8_t*  s2    = ws + W1TD_BYTES + MASK_BYTES + R_BYTES;
  double*   R3    = (double*)(ws + W1TD_BYTES + MASK_BYTES + R_BYTES + S2_BYTES);

  k0_transpose<<<99, 256, 0, stream>>>(w1, w1td);
  k1_layer1<<<dim3(NW, NB), 64, 0, stream>>>(x, masks);
  k2_fc1<<<dim3(NB, NT / 4), 256, 0, stream>>>(w1td, masks, R);
  k3_spike2<<<4, 64, 0, stream>>>(R, s2);
  k4_fc2<<<(NB * NOUT * NT + 255) / 256, 256, 0, stream>>>(w2, s2, R3);
  k5_out<<<3, 64, 0, stream>>>(R3, out);
}

// Round 7
// 316.162 us; speedup vs baseline: 1.0589x; 1.0589x over previous
//
#include <hip/hip_runtime.h>
#include <stdint.h>

#define NB 8
#define F_IN 6300
#define NT 500
#define HID 32
#define NOUT 20
#define NW 99   // u64 mask words per (b,t) row: ceil(6300/64)

// float32 constants, rounded exactly as np.float32 would round the doubles
#define D_SR   0.7788007830714049f     // exp(-1/4)
#define S_SR   0.6795704571147613f     // e/4
#define D_REF  0.36787944117144233f    // exp(-1)
#define C_REF  -5.43656365691809f      // -2*e

// ---------------- K0: transpose w1 [32][6300] -> w1t [6300][32] (f32) ----------------
__global__ __launch_bounds__(256) void k0_transpose(const float* __restrict__ w1,
                                                    float* __restrict__ w1t) {
  __shared__ float tl[64][33];
  const int f0 = blockIdx.x * 64;
  const int tid = threadIdx.x;
  const int r = tid & 63, g = tid >> 6;
#pragma unroll
  for (int oo = 0; oo < 32; oo += 4) {
    int o = oo + g;
    int f = f0 + r;
    tl[r][o] = (f < F_IN) ? w1[o * F_IN + f] : 0.f;
  }
  __syncthreads();
#pragma unroll
  for (int k = 0; k < 8; k++) {
    int idx = k * 256 + tid;                 // 0..2047 within tile
    int rr = idx >> 5, cc = idx & 31;
    int f = f0 + rr;
    if (f < F_IN) w1t[(size_t)f * 32 + cc] = tl[rr][cc];
  }
}

// ---------------- K1: layer 1 (psp -> spike), exact f32 ----------------
// One wave per (b, 64-f word); 1-wave blocks => no barriers. 5 chunks of 100 t.
// float4 loads ALONG t (coalesced), transposed through LDS tile[100][65];
// chunk c+1's global loads fly while chunk c computes.
#define CH_T 100

__global__ __launch_bounds__(64) void k1_layer1(const float* __restrict__ x,
                                                uint64_t* __restrict__ masks) {
  __shared__ float tile[CH_T][65];          // 26 KB -> 6 blocks/CU
  const int wi = blockIdx.x;                // 0..98
  const int b  = blockIdx.y;
  const int lane = threadIdx.x;
  const int f = wi * 64 + lane;
  const float vm = (f < F_IN) ? 1.0f : 0.0f;
  const float* xblk = x + (size_t)b * F_IN * NT;
  uint64_t* mrow = masks + ((size_t)b * NW + wi) * NT;   // contiguous in t

  int goff[25], fidv[25], jv[25];
#pragma unroll
  for (int k = 0; k < 25; k++) {
    int idx = k * 64 + lane;
    int fid = idx / 25;
    int j = idx - fid * 25;
    int rf = wi * 64 + fid;
    if (rf >= F_IN) rf = F_IN - 1;          // clamp: in-bounds reads, zeroed by vm
    goff[k] = rf * NT + 4 * j;
    fidv[k] = fid;
    jv[k] = j;
  }

  float z1 = 0.f, y1 = 0.f, zr = 0.f, yr = 0.f;
  float4 ld[25];
#pragma unroll
  for (int k = 0; k < 25; k++) ld[k] = *(const float4*)(xblk + goff[k]);

  for (int c = 0; c < 5; c++) {
#pragma unroll
    for (int k = 0; k < 25; k++) {
      int r = 4 * jv[k], fd = fidv[k];
      tile[r + 0][fd] = ld[k].x;
      tile[r + 1][fd] = ld[k].y;
      tile[r + 2][fd] = ld[k].z;
      tile[r + 3][fd] = ld[k].w;
    }
    if (c + 1 < 5) {
      const float* gb = xblk + (c + 1) * CH_T;
#pragma unroll
      for (int k = 0; k < 25; k++) ld[k] = *(const float4*)(gb + goff[k]);
    }
    uint64_t keep0 = 0, keep1 = 0;
#pragma unroll
    for (int tc = 0; tc < CH_T; tc++) {
      float xi = tile[tc][lane] * vm;
      y1 = __fmul_rn(D_SR, __fadd_rn(y1, z1));        // y = d*(y+z)
      z1 = __fadd_rn(__fmul_rn(D_SR, z1), xi);        // z = d*z + x
      float p = __fmul_rn(S_SR, y1);
      yr = __fmul_rn(D_REF, __fadd_rn(yr, zr));
      float u = __fadd_rn(p, __fmul_rn(C_REF, yr));
      bool s = (u >= 1.0f);
      zr = __fadd_rn(__fmul_rn(D_REF, zr), s ? 1.0f : 0.0f);
      uint64_t m = __ballot(s);
      if (tc < 64) { if (lane == tc)      keep0 = m; }
      else         { if (lane == tc - 64) keep1 = m; }
    }
    uint64_t* mp = mrow + c * CH_T;
    mp[lane] = keep0;
    if (lane < CH_T - 64) mp[64 + lane] = keep1;
  }
}

// ---------------- K2: sparse fc1: R[b,o,t] = sum_{f active} w1t[f][o] (f64) ----------------
// 512-thread blocks: 8 waves = 4 t x 2 f-segments. Each wave: halves take even/odd
// u64 words of its segment; 4-way batched bit extraction -> 4 independent row loads.
__global__ __launch_bounds__(512) void k2_fc1(const float* __restrict__ w1t,
                                              const uint64_t* __restrict__ masks,
                                              double* __restrict__ R) {
  __shared__ double part[8][32];
  const int tid = threadIdx.x;
  const int wv = tid >> 6;            // 0..7
  const int lane = tid & 63;
  const int half = lane >> 5;
  const int o = lane & 31;
  const int b = blockIdx.x;
  const int t = blockIdx.y * 4 + (wv & 3);
  const int seg = wv >> 2;            // 0: wi 0..49, 1: wi 50..98
  const int wbeg = seg * 50, wend = seg ? NW : 50;
  const uint64_t* mbase = masks + (size_t)b * NW * NT + t;
  const char* wrow = (const char*)w1t + o * 4;
  double acc = 0.0;

  int wi = wbeg + half;
  uint64_t mcur = (wi < wend) ? mbase[(size_t)wi * NT] : 0;
  for (; wi < wend; wi += 2) {
    uint64_t mnext = (wi + 2 < wend) ? mbase[(size_t)(wi + 2) * NT] : 0;
    const uint32_t base0 = ((uint32_t)wi << 13);     // wi*64 rows * 128 B
    // low 32 bits, then high 32 bits (ascending f)
    uint32_t w = (uint32_t)mcur;
    uint32_t boff = base0;
#pragma unroll
    for (int sub = 0; sub < 2; sub++) {
      while (w) {
        uint32_t i0 = __builtin_ctz(w);                 uint32_t w1_ = w & (w - 1);
        uint32_t i1 = w1_ ? __builtin_ctz(w1_) : 0u;    uint32_t w2_ = w1_ ? (w1_ & (w1_ - 1)) : 0u;
        uint32_t i2 = w2_ ? __builtin_ctz(w2_) : 0u;    uint32_t w3_ = w2_ ? (w2_ & (w2_ - 1)) : 0u;
        uint32_t i3 = w3_ ? __builtin_ctz(w3_) : 0u;    w = w3_ ? (w3_ & (w3_ - 1)) : 0u;
        float a0 = *(const float*)(wrow + boff + (i0 << 7));
        float a1 = *(const float*)(wrow + boff + (i1 << 7));
        float a2 = *(const float*)(wrow + boff + (i2 << 7));
        float a3 = *(const float*)(wrow + boff + (i3 << 7));
        a1 = w1_ ? a1 : 0.0f;
        a2 = w2_ ? a2 : 0.0f;
        a3 = w3_ ? a3 : 0.0f;
        acc += (double)a0;      // += 0.0 is exact, so tail slots are harmless
        acc += (double)a1;
        acc += (double)a2;
        acc += (double)a3;
      }
      w = (uint32_t)(mcur >> 32);
      boff = base0 + (32u << 7);
    }
    mcur = mnext;
  }
  // combine even/odd halves (lane ^ 32)
  int hi2 = __shfl_xor(__double2hiint(acc), 32);
  int lo2 = __shfl_xor(__double2loint(acc), 32);
  acc += __hiloint2double(hi2, lo2);
  if (half == 0) part[wv][o] = acc;
  __syncthreads();
  if (wv < 4 && half == 0) {
    double tot = part[wv][o] + part[wv + 4][o];   // seg0 + seg1 (ascending f)
    R[((size_t)b * HID + o) * NT + t] = tot;
  }
}

// ---------------- shared f64 psp+spike step (layers 2/3) ----------------
__device__ __forceinline__ bool snn_step(double ri, double& z2, double& y2,
                                         double& zr, double& yr) {
  const double dsr = (double)D_SR, ssr = (double)S_SR;
  const double dre = (double)D_REF, cr = (double)C_REF;
  y2 = dsr * (y2 + z2);
  z2 = dsr * z2 + ri;
  double p = ssr * y2;
  yr = dre * (yr + zr);
  double u = p + cr * yr;
  bool s = (u >= 1.0);
  zr = dre * zr + (s ? 1.0 : 0.0);
  return s;
}

// ---------------- K345: fused layer-2 spike + fc2 + layer-3 spike -> out ----------------
// One block per b. Phase 1: wave 0 runs layer-2 recurrence (32 h lanes), spikes
// ballot'd into LDS bitmasks. Phase 2: 240 threads do fc2 via ctz-driven LDS dot
// (ascending h). Phase 3: lanes 0..19 run layer-3 recurrence, write output.
__global__ __launch_bounds__(256) void k345(const double* __restrict__ R,
                                            const float* __restrict__ w2,
                                            float* __restrict__ out) {
  __shared__ uint32_t s2m[NT];          // layer-2 spikes, bit h of word t
  __shared__ float    w2l[NOUT][33];    // padded
  __shared__ double   r3[NT][NOUT];     // 80 KB
  const int tid = threadIdx.x;
  const int b = blockIdx.x;

  if (tid >= 64) {
    // waves 1-3: stage w2 into LDS while wave 0 runs phase 1
    for (int i = tid - 64; i < NOUT * HID; i += 192)
      w2l[i >> 5][i & 31] = w2[i];
  } else {
    // ---- phase 1: layer-2 psp + spike, 32 channels ----
    const int lane = tid;
    const int h = lane & 31;
    const bool act = lane < HID;
    const double2* r2 = (const double2*)(R + ((size_t)b * HID + h) * NT);
    double z2 = 0, y2 = 0, zr = 0, yr = 0;
    double2 g0a = r2[0], g0b = r2[1];
    double2 g1a = r2[2], g1b = r2[3];
    double2 g2a = r2[4], g2b = r2[5];
    double2 g3a = r2[6], g3b = r2[7];
    for (int g = 0; g < 125; g++) {
      const int t = g * 4;
      double v0 = act ? g0a.x : 0.0, v1 = act ? g0a.y : 0.0;
      double v2 = act ? g0b.x : 0.0, v3 = act ? g0b.y : 0.0;
      uint64_t m0 = __ballot(snn_step(v0, z2, y2, zr, yr) && act);
      uint64_t m1 = __ballot(snn_step(v1, z2, y2, zr, yr) && act);
      uint64_t m2 = __ballot(snn_step(v2, z2, y2, zr, yr) && act);
      uint64_t m3 = __ballot(snn_step(v3, z2, y2, zr, yr) && act);
      if (lane == 0) {
        s2m[t + 0] = (uint32_t)m0;
        s2m[t + 1] = (uint32_t)m1;
        s2m[t + 2] = (uint32_t)m2;
        s2m[t + 3] = (uint32_t)m3;
      }
      g0a = g1a; g0b = g1b; g1a = g2a; g1b = g2b; g2a = g3a; g2b = g3b;
      if (g + 4 < 125) { g3a = r2[(g + 4) * 2]; g3b = r2[(g + 4) * 2 + 1]; }
    }
  }
  __syncthreads();

  // ---- phase 2: fc2 r3[t][o] = sum_h w2[o,h]*s2[t,h] (f64, ascending h) ----
  if (tid < 240) {
    const int o = tid / 12;            // 0..19
    const int sl = tid % 12;           // t = sl, sl+12, ...
    for (int t = sl; t < NT; t += 12) {
      uint32_t m = s2m[t];
      double acc = 0.0;
      while (m) {
        int i = __builtin_ctz(m);
        m &= m - 1;
        acc += (double)w2l[o][i];
      }
      r3[t][o] = acc;
    }
  }
  __syncthreads();

  // ---- phase 3: layer-3 psp + spike -> out[b][o][t] ----
  if (tid < NOUT) {
    const int o = tid;
    float* orow = out + ((size_t)b * NOUT + o) * NT;
    double z2 = 0, y2 = 0, zr = 0, yr = 0;
    for (int t = 0; t < NT; t++) {
      bool s = snn_step(r3[t][o], z2, y2, zr, yr);
      orow[t] = s ? 1.0f : 0.0f;
    }
  }
}

extern "C" void kernel_launch(void* const* d_in, const int* in_sizes, int n_in,
                              void* d_out, int out_size, void* d_ws, size_t ws_size,
                              hipStream_t stream) {
  const float* x  = (const float*)d_in[0];   // [8,6300,500]
  const float* w1 = (const float*)d_in[1];   // [32,6300]
  const float* w2 = (const float*)d_in[2];   // [20,32]
  float* out = (float*)d_out;                // [8,20,500]

  uint8_t* ws = (uint8_t*)d_ws;
  const size_t W1T_BYTES  = (size_t)F_IN * HID * 4;        //   806,400
  const size_t MASK_BYTES = (size_t)NB * NW * NT * 8;      // 3,168,000
  float*    w1t   = (float*)ws;
  uint64_t* masks = (uint64_t*)(ws + W1T_BYTES);
  double*   R     = (double*)(ws + W1T_BYTES + MASK_BYTES);

  k0_transpose<<<99, 256, 0, stream>>>(w1, w1t);
  k1_layer1<<<dim3(NW, NB), 64, 0, stream>>>(x, masks);
  k2_fc1<<<dim3(NB, NT / 4), 512, 0, stream>>>(w1t, masks, R);
  k345<<<NB, 256, 0, stream>>>(R, w2, out);
}